// Round 4
// baseline (824.405 us; speedup 1.0000x reference)
//
#include <hip/hip_runtime.h>
#include <hip/hip_bf16.h>

#define B_   2
#define H_   16
#define SQ_  2048
#define SK_  2048
#define D_   128
#define QT   128
#define KT   64
#define NITER (SK_/KT)

using bf16x8 = __attribute__((ext_vector_type(8))) __bf16;
using bf16x4 = __attribute__((ext_vector_type(4))) __bf16;
using f32x4  = __attribute__((ext_vector_type(4))) float;
using i32x4  = __attribute__((ext_vector_type(4))) int;

#define MFMA16(a,b,c) __builtin_amdgcn_mfma_f32_16x16x32_bf16(a,b,c,0,0,0)

// ws layout (bytes): tiles dense; LDS padding applied at ds_write time.
#define QOFF 0u              // bf16 Q, original layout (16.8 MB)
#define KOFF (1u<<25)        // bf16 K, original layout (tiles are contiguous rows)
#define VOFF (1u<<26)        // bf16 V^T tiles [bh*32+kt][128][64]

// LDS pitches (elements). dword strides 68/36/36 are ===4 (mod 32): every b128
// access pattern lands at the wave64 minimum of 8 dw/bank (hand-verified for
// kf/vf/pf reads and K/V/P writes).
#define KPITCH 136
#define VPITCH 72
#define PPITCH 72
#define KB_BYTES (KT*KPITCH*2)   // 17408
#define VB_BYTES (D_*VPITCH*2)   // 18432
#define PB_BYTES (QT*PPITCH*2)   // 18432

__device__ __forceinline__ bf16x8 mask8(bf16x8 p, i32x4 a, i32x4 b) {
    bf16x8 r;
    r[0] = a[0] ? p[0] : (__bf16)0.0f;
    r[1] = a[1] ? p[1] : (__bf16)0.0f;
    r[2] = a[2] ? p[2] : (__bf16)0.0f;
    r[3] = a[3] ? p[3] : (__bf16)0.0f;
    r[4] = b[0] ? p[4] : (__bf16)0.0f;
    r[5] = b[1] ? p[5] : (__bf16)0.0f;
    r[6] = b[2] ? p[6] : (__bf16)0.0f;
    r[7] = b[3] ? p[7] : (__bf16)0.0f;
    return r;
}

// ---------- fused prepass: Q/K flat f32->bf16 cast + V tile transpose ----------
__global__ __launch_bounds__(256)
void prep(const float* __restrict__ Q, const float* __restrict__ K,
          const float* __restrict__ V, char* __restrict__ ws)
{
    __shared__ __align__(16) __bf16 vlds[64 * 132];
    const int blk = blockIdx.x;     // 0..1023 (= bh*32 + kt for the V tile)
    const int t   = threadIdx.x;

    // Q and K flat cast: 2048 float4 per block (1024*2048 = full 2.097M float4)
    {
        const float4* q4 = (const float4*)Q;
        const float4* k4 = (const float4*)K;
        bf16x4* qd = (bf16x4*)(ws + QOFF);
        bf16x4* kd = (bf16x4*)(ws + KOFF);
        #pragma unroll
        for (int i = 0; i < 8; ++i) {
            size_t f = (size_t)blk * 2048 + t + 256 * i;
            float4 a = q4[f];
            qd[f] = (bf16x4){ (__bf16)a.x, (__bf16)a.y, (__bf16)a.z, (__bf16)a.w };
            float4 b = k4[f];
            kd[f] = (bf16x4){ (__bf16)b.x, (__bf16)b.y, (__bf16)b.z, (__bf16)b.w };
        }
    }
    // V 64x128 tile -> dense V^T tile [d=128][k=64]  (verified in round 3)
    {
        const float4* src = (const float4*)(V + (size_t)blk * KT * D_);  // 2048 float4
        #pragma unroll
        for (int i = 0; i < 8; ++i) {
            int f = t + 256 * i;
            float4 v = src[f];
            int row = f >> 5, col = f & 31;
            *(bf16x4*)&vlds[row * 132 + col * 4] =
                (bf16x4){ (__bf16)v.x, (__bf16)v.y, (__bf16)v.z, (__bf16)v.w };
        }
        __syncthreads();
        __bf16* dst = (__bf16*)(ws + VOFF) + (size_t)blk * (D_ * KT);
        const int d = t >> 1, h = t & 1;
        #pragma unroll
        for (int c = 0; c < 4; ++c) {
            bf16x8 frag;
            #pragma unroll
            for (int j = 0; j < 8; ++j) frag[j] = vlds[(h * 32 + c * 8 + j) * 132 + d];
            *(bf16x8*)&dst[d * KT + h * 32 + c * 8] = frag;
        }
    }
}

// ---------- main kernel: fully software-pipelined (K/V and mask 1 iter ahead) ----------
__global__ __launch_bounds__(256, 2)
void attn_drop_kernel(const char* __restrict__ ws,
                      const int*  __restrict__ M,
                      float* __restrict__ Out)
{
    __shared__ __align__(16) char smem[KB_BYTES + VB_BYTES + PB_BYTES];  // 54272
    __bf16* Kb = (__bf16*)smem;
    __bf16* Vb = (__bf16*)(smem + KB_BYTES);
    __bf16* Pb = (__bf16*)(smem + KB_BYTES + VB_BYTES);

    const int tid  = threadIdx.x;
    const int wave = tid >> 6;
    const int lane = tid & 63;
    const int quad = lane >> 4;
    const int ln   = lane & 15;

    const int bh = blockIdx.x >> 4;
    const int qb = blockIdx.x & 15;

    const __bf16* Qbf = (const __bf16*)(ws + QOFF);
    const __bf16* Kbf = (const __bf16*)(ws + KOFF);
    const __bf16* Vtt = (const __bf16*)(ws + VOFF);
    const int* mbase = M + ((size_t)bh * SQ_ + (size_t)qb * QT) * SK_;
    float* optr = Out + ((size_t)bh * SQ_ + (size_t)qb * QT) * D_;

    // Q fragments register-resident for the whole loop
    bf16x8 qf[2][4];
    #pragma unroll
    for (int rt = 0; rt < 2; ++rt)
        #pragma unroll
        for (int s = 0; s < 4; ++s)
            qf[rt][s] = *(const bf16x8*)&Qbf[((size_t)bh*SQ_ + qb*QT + 32*wave + 16*rt + ln)*D_ + 32*s + 8*quad];

    f32x4 Oacc[2][8];
    #pragma unroll
    for (int rt = 0; rt < 2; ++rt)
        #pragma unroll
        for (int dt = 0; dt < 8; ++dt)
            Oacc[rt][dt] = (f32x4){0.f, 0.f, 0.f, 0.f};

    // ---- pipeline prologue: K/V tile 0 -> regs, mask tile 0 -> mreg[0]
    bf16x8 kreg[4], vreg[4];
    i32x4  mreg[2][2][2][2];   // [parity][rt][ks][i]
    {
        const __bf16* kp = Kbf + (size_t)bh * SK_ * D_;
        const __bf16* vp = Vtt + (size_t)(bh * 32) * (D_ * KT);
        #pragma unroll
        for (int j = 0; j < 4; ++j) {
            kreg[j] = *(const bf16x8*)&kp[j*2048 + tid*8];
            vreg[j] = *(const bf16x8*)&vp[j*2048 + tid*8];
        }
        #pragma unroll
        for (int rt = 0; rt < 2; ++rt)
            #pragma unroll
            for (int ks = 0; ks < 2; ++ks)
                #pragma unroll
                for (int i = 0; i < 2; ++i)
                    mreg[0][rt][ks][i] = __builtin_nontemporal_load(
                        (const i32x4*)&mbase[(size_t)(32*wave + 16*rt + ln)*SK_ + 32*ks + 8*quad + 4*i]);
    }

    #pragma unroll 2          // makes mreg parity indexing static
    for (int kt = 0; kt < NITER; ++kt) {
        const int par = kt & 1;
        __syncthreads();       // prev iter's LDS reads complete
        // regs -> padded LDS (conflict-free, see pitch note)
        #pragma unroll
        for (int j = 0; j < 4; ++j) {
            *(bf16x8*)&Kb[(16*j + (tid>>4))*KPITCH + (tid&15)*8] = kreg[j];
            *(bf16x8*)&Vb[(32*j + (tid>>3))*VPITCH + (tid&7)*8]  = vreg[j];
        }
        __syncthreads();       // tiles ready

        // ---- prefetch NEXT iter's K/V tiles and mask (land during compute below)
        {
            const int nkt = (kt + 1 < NITER) ? kt + 1 : kt;
            const __bf16* kp = Kbf + ((size_t)bh*SK_ + nkt*KT) * D_;
            const __bf16* vp = Vtt + (size_t)(bh*32 + nkt) * (D_*KT);
            #pragma unroll
            for (int j = 0; j < 4; ++j) {
                kreg[j] = *(const bf16x8*)&kp[j*2048 + tid*8];
                vreg[j] = *(const bf16x8*)&vp[j*2048 + tid*8];
            }
            #pragma unroll
            for (int rt = 0; rt < 2; ++rt)
                #pragma unroll
                for (int ks = 0; ks < 2; ++ks)
                    #pragma unroll
                    for (int i = 0; i < 2; ++i)
                        mreg[par^1][rt][ks][i] = __builtin_nontemporal_load(
                            (const i32x4*)&mbase[(size_t)(32*wave + 16*rt + ln)*SK_ + nkt*KT + 32*ks + 8*quad + 4*i]);
        }

        // ---- S = Q K^T
        f32x4 S[2][4];
        #pragma unroll
        for (int rt = 0; rt < 2; ++rt)
            #pragma unroll
            for (int ct = 0; ct < 4; ++ct)
                S[rt][ct] = (f32x4){0.f, 0.f, 0.f, 0.f};

        #pragma unroll
        for (int s = 0; s < 4; ++s)
            #pragma unroll
            for (int ct = 0; ct < 4; ++ct) {
                bf16x8 kf = *(const bf16x8*)&Kb[(16*ct + ln)*KPITCH + 32*s + 8*quad];
                S[0][ct] = MFMA16(qf[0][s], kf, S[0][ct]);
                S[1][ct] = MFMA16(qf[1][s], kf, S[1][ct]);
            }

        // ---- P -> LDS (C-layout; wave-private rows, no barrier needed)
        #pragma unroll
        for (int rt = 0; rt < 2; ++rt)
            #pragma unroll
            for (int ct = 0; ct < 4; ++ct) {
                int row0 = 32*wave + 16*rt + 4*quad;
                #pragma unroll
                for (int r = 0; r < 4; ++r)
                    Pb[(row0 + r)*PPITCH + 16*ct + ln] = (__bf16)S[rt][ct][r];
            }

        // ---- O += dropout(P) V  (mask from the prefetched parity buffer)
        #pragma unroll
        for (int ks = 0; ks < 2; ++ks) {
            bf16x8 pf0 = mask8(*(const bf16x8*)&Pb[(32*wave +      ln)*PPITCH + 32*ks + 8*quad],
                               mreg[par][0][ks][0], mreg[par][0][ks][1]);
            bf16x8 pf1 = mask8(*(const bf16x8*)&Pb[(32*wave + 16 + ln)*PPITCH + 32*ks + 8*quad],
                               mreg[par][1][ks][0], mreg[par][1][ks][1]);
            #pragma unroll
            for (int dt = 0; dt < 8; ++dt) {
                bf16x8 vf = *(const bf16x8*)&Vb[(16*dt + ln)*VPITCH + 32*ks + 8*quad];
                Oacc[0][dt] = MFMA16(pf0, vf, Oacc[0][dt]);
                Oacc[1][dt] = MFMA16(pf1, vf, Oacc[1][dt]);
            }
        }
    }

    // ---- epilogue: folded scale 2*sqrt(D) = 16*sqrt(2), nontemporal stores
    const float SCALE = 22.62741699796952f;
    #pragma unroll
    for (int rt = 0; rt < 2; ++rt)
        #pragma unroll
        for (int dt = 0; dt < 8; ++dt) {
            int row0 = 32*wave + 16*rt + 4*quad;
            #pragma unroll
            for (int r = 0; r < 4; ++r)
                __builtin_nontemporal_store(Oacc[rt][dt][r] * SCALE,
                    &optr[(size_t)(row0 + r)*D_ + 16*dt + ln]);
        }
}

extern "C" void kernel_launch(void* const* d_in, const int* in_sizes, int n_in,
                              void* d_out, int out_size, void* d_ws, size_t ws_size,
                              hipStream_t stream) {
    (void)in_sizes; (void)n_in; (void)ws_size; (void)out_size;
    const float* Q = (const float*)d_in[0];
    const float* K = (const float*)d_in[1];
    const float* V = (const float*)d_in[2];
    const int*   M = (const int*)d_in[3];
    float* Out = (float*)d_out;
    char* ws = (char*)d_ws;

    prep<<<dim3(B_*H_*(SK_/KT)), 256, 0, stream>>>(Q, K, V, ws);
    attn_drop_kernel<<<dim3(B_*H_*(SQ_/QT)), 256, 0, stream>>>(ws, M, Out);
}

// Round 6
// 823.818 us; speedup vs baseline: 1.0007x; 1.0007x over previous
//
#include <hip/hip_runtime.h>
#include <hip/hip_bf16.h>

#define B_   2
#define H_   16
#define SQ_  2048
#define SK_  2048
#define D_   128
#define QT   128
#define KT   64
#define NITER (SK_/KT)
#define MWORDS (SK_/64)          // 32 uint64 words per mask row

using bf16x8 = __attribute__((ext_vector_type(8))) __bf16;
using bf16x4 = __attribute__((ext_vector_type(4))) __bf16;
using f32x4  = __attribute__((ext_vector_type(4))) float;
using i32x4  = __attribute__((ext_vector_type(4))) int;
typedef unsigned long long u64;
typedef unsigned int u32;

#define MFMA16(a,b,c) __builtin_amdgcn_mfma_f32_16x16x32_bf16(a,b,c,0,0,0)

// ws layout (bytes)
#define QOFF 0u                  // bf16 Q, original layout (16.8 MB)
#define KOFF (1u<<25)            // bf16 K, original layout
#define VOFF (1u<<26)            // bf16 V^T tiles [bh*32+kt][128][64]
#define MOFF (3u<<25)            // bitmask: u64 word per (row, 64-col group), 16.8 MB

// LDS pitches (elements); dword strides ===4 (mod 32) -> all b128 patterns at
// the wave64 minimum of 8 dw/bank (audited; SQ_LDS_BANK_CONFLICT=0 in r3/r4).
#define KPITCH 136
#define VPITCH 72
#define PPITCH 72
#define KB_BYTES (KT*KPITCH*2)
#define VB_BYTES (D_*VPITCH*2)
#define PB_BYTES (QT*PPITCH*2)

// bit e of `byte` keeps element e (PV A-fragment order: col = 32ks+8quad+e)
__device__ __forceinline__ bf16x8 mask8b(bf16x8 p, u32 byte) {
    bf16x8 r;
    #pragma unroll
    for (int e = 0; e < 8; ++e)
        r[e] = (byte & (1u << e)) ? p[e] : (__bf16)0.0f;
    return r;
}

// ---------- prepass A: compress int32 mask -> bitmask (bit b of word w = col 64w+b) ----------
__global__ __launch_bounds__(256)
void compress_mask(const int* __restrict__ M, char* __restrict__ ws)
{
    const int wave = threadIdx.x >> 6, lane = threadIdx.x & 63;
    u64* out = (u64*)(ws + MOFF);
    const int sh = 4 * (lane & 15);
    #pragma unroll 2
    for (int round = 0; round < 16; ++round) {
        // wave-base int index; lane covers ints base+4L..base+4L+3 (contiguous i32x4)
        size_t base = (((size_t)blockIdx.x * 16 + round) * 4 + wave) * 256;
        i32x4 m = __builtin_nontemporal_load((const i32x4*)(M + base) + lane);
        u32 nib = (m[0] != 0) | ((m[1] != 0) << 1) | ((m[2] != 0) << 2) | ((m[3] != 0) << 3);
        u64 v = (u64)nib << sh;            // pre-shift into word position
        v |= __shfl_xor(v, 1);             // OR-reduce nibbles within each 16-lane group
        v |= __shfl_xor(v, 2);
        v |= __shfl_xor(v, 4);
        v |= __shfl_xor(v, 8);
        if ((lane & 15) == 0)
            out[(base >> 6) + (lane >> 4)] = v;
    }
}

// ---------- prepass B: Q/K flat f32->bf16 cast + V tile transpose ----------
__global__ __launch_bounds__(256)
void prep(const float* __restrict__ Q, const float* __restrict__ K,
          const float* __restrict__ V, char* __restrict__ ws)
{
    __shared__ __align__(16) __bf16 vlds[64 * 132];
    const int blk = blockIdx.x;     // 0..1023 (= bh*32 + kt for the V tile)
    const int t   = threadIdx.x;
    {
        const float4* q4 = (const float4*)Q;
        const float4* k4 = (const float4*)K;
        bf16x4* qd = (bf16x4*)(ws + QOFF);
        bf16x4* kd = (bf16x4*)(ws + KOFF);
        #pragma unroll
        for (int i = 0; i < 8; ++i) {
            size_t f = (size_t)blk * 2048 + t + 256 * i;
            float4 a = q4[f];
            qd[f] = (bf16x4){ (__bf16)a.x, (__bf16)a.y, (__bf16)a.z, (__bf16)a.w };
            float4 b = k4[f];
            kd[f] = (bf16x4){ (__bf16)b.x, (__bf16)b.y, (__bf16)b.z, (__bf16)b.w };
        }
    }
    {
        const float4* src = (const float4*)(V + (size_t)blk * KT * D_);
        #pragma unroll
        for (int i = 0; i < 8; ++i) {
            int f = t + 256 * i;
            float4 v = src[f];
            int row = f >> 5, col = f & 31;
            *(bf16x4*)&vlds[row * 132 + col * 4] =
                (bf16x4){ (__bf16)v.x, (__bf16)v.y, (__bf16)v.z, (__bf16)v.w };
        }
        __syncthreads();
        __bf16* dst = (__bf16*)(ws + VOFF) + (size_t)blk * (D_ * KT);
        const int d = t >> 1, h = t & 1;
        #pragma unroll
        for (int c = 0; c < 4; ++c) {
            bf16x8 frag;
            #pragma unroll
            for (int j = 0; j < 8; ++j) frag[j] = vlds[(h * 32 + c * 8 + j) * 132 + d];
            *(bf16x8*)&dst[d * KT + h * 32 + c * 8] = frag;
        }
    }
}

// ---------- main kernel ----------
__global__ __launch_bounds__(256, 2)
void attn_drop_kernel(const char* __restrict__ ws, float* __restrict__ Out)
{
    __shared__ __align__(16) char smem[KB_BYTES + VB_BYTES + PB_BYTES];  // 54272
    __bf16* Kb = (__bf16*)smem;
    __bf16* Vb = (__bf16*)(smem + KB_BYTES);
    __bf16* Pb = (__bf16*)(smem + KB_BYTES + VB_BYTES);

    const int tid  = threadIdx.x;
    const int wave = tid >> 6;
    const int lane = tid & 63;
    const int quad = lane >> 4;
    const int ln   = lane & 15;
    const int qs   = 8 * quad;

    const int bh = blockIdx.x >> 4;
    const int qb = blockIdx.x & 15;

    const __bf16* Qbf = (const __bf16*)(ws + QOFF);
    const __bf16* Kbf = (const __bf16*)(ws + KOFF);
    const __bf16* Vtt = (const __bf16*)(ws + VOFF);
    const u64*    Mb  = (const u64*)(ws + MOFF);
    float* optr = Out + ((size_t)bh * SQ_ + (size_t)qb * QT) * D_;

    // bitmask row bases (u64 index): one word per 64 cols, MWORDS per row
    const size_t mrow0 = ((size_t)bh * SQ_ + qb * QT + 32 * wave + ln) * MWORDS;
    const size_t mrow1 = mrow0 + 16 * MWORDS;

    // Q fragments register-resident for the whole loop
    bf16x8 qf[2][4];
    #pragma unroll
    for (int rt = 0; rt < 2; ++rt)
        #pragma unroll
        for (int s = 0; s < 4; ++s)
            qf[rt][s] = *(const bf16x8*)&Qbf[((size_t)bh*SQ_ + qb*QT + 32*wave + 16*rt + ln)*D_ + 32*s + 8*quad];

    f32x4 Oacc[2][8];
    #pragma unroll
    for (int rt = 0; rt < 2; ++rt)
        #pragma unroll
        for (int dt = 0; dt < 8; ++dt)
            Oacc[rt][dt] = (f32x4){0.f, 0.f, 0.f, 0.f};

    // pipeline prologue: K/V tile 0 + mask words 0
    bf16x8 kreg[4], vreg[4];
    u64 mcur0, mcur1;
    {
        const __bf16* kp = Kbf + (size_t)bh * SK_ * D_;
        const __bf16* vp = Vtt + (size_t)(bh * 32) * (D_ * KT);
        #pragma unroll
        for (int j = 0; j < 4; ++j) {
            kreg[j] = *(const bf16x8*)&kp[j*2048 + tid*8];
            vreg[j] = *(const bf16x8*)&vp[j*2048 + tid*8];
        }
        mcur0 = Mb[mrow0];
        mcur1 = Mb[mrow1];
    }

    #pragma unroll 1
    for (int kt = 0; kt < NITER; ++kt) {
        __syncthreads();
        #pragma unroll
        for (int j = 0; j < 4; ++j) {
            *(bf16x8*)&Kb[(16*j + (tid>>4))*KPITCH + (tid&15)*8] = kreg[j];
            *(bf16x8*)&Vb[(32*j + (tid>>3))*VPITCH + (tid&7)*8]  = vreg[j];
        }
        __syncthreads();

        // prefetch NEXT iter's K/V tiles + mask words (land during compute)
        const int nkt = (kt + 1 < NITER) ? kt + 1 : kt;
        u64 mnxt0, mnxt1;
        {
            const __bf16* kp = Kbf + ((size_t)bh*SK_ + nkt*KT) * D_;
            const __bf16* vp = Vtt + (size_t)(bh*32 + nkt) * (D_*KT);
            #pragma unroll
            for (int j = 0; j < 4; ++j) {
                kreg[j] = *(const bf16x8*)&kp[j*2048 + tid*8];
                vreg[j] = *(const bf16x8*)&vp[j*2048 + tid*8];
            }
            mnxt0 = Mb[mrow0 + nkt];
            mnxt1 = Mb[mrow1 + nkt];
        }

        // ---- S = Q K^T
        f32x4 S[2][4];
        #pragma unroll
        for (int rt = 0; rt < 2; ++rt)
            #pragma unroll
            for (int ct = 0; ct < 4; ++ct)
                S[rt][ct] = (f32x4){0.f, 0.f, 0.f, 0.f};
        #pragma unroll
        for (int s = 0; s < 4; ++s)
            #pragma unroll
            for (int ct = 0; ct < 4; ++ct) {
                bf16x8 kf = *(const bf16x8*)&Kb[(16*ct + ln)*KPITCH + 32*s + 8*quad];
                S[0][ct] = MFMA16(qf[0][s], kf, S[0][ct]);
                S[1][ct] = MFMA16(qf[1][s], kf, S[1][ct]);
            }

        // ---- P -> LDS (C-layout; wave-private rows)
        #pragma unroll
        for (int rt = 0; rt < 2; ++rt)
            #pragma unroll
            for (int ct = 0; ct < 4; ++ct) {
                int row0 = 32*wave + 16*rt + 4*quad;
                #pragma unroll
                for (int r = 0; r < 4; ++r)
                    Pb[(row0 + r)*PPITCH + 16*ct + ln] = (__bf16)S[rt][ct][r];
            }

        // ---- O += dropout(P) V   (bits: col = kt*64 + 32ks + 8quad + e)
        #pragma unroll
        for (int ks = 0; ks < 2; ++ks) {
            u32 h0 = (u32)(mcur0 >> (32 * ks));
            u32 h1 = (u32)(mcur1 >> (32 * ks));
            u32 b0 = (h0 >> qs) & 0xffu;
            u32 b1 = (h1 >> qs) & 0xffu;
            bf16x8 pf0 = mask8b(*(const bf16x8*)&Pb[(32*wave +      ln)*PPITCH + 32*ks + 8*quad], b0);
            bf16x8 pf1 = mask8b(*(const bf16x8*)&Pb[(32*wave + 16 + ln)*PPITCH + 32*ks + 8*quad], b1);
            #pragma unroll
            for (int dt = 0; dt < 8; ++dt) {
                bf16x8 vf = *(const bf16x8*)&Vb[(16*dt + ln)*VPITCH + 32*ks + 8*quad];
                Oacc[0][dt] = MFMA16(pf0, vf, Oacc[0][dt]);
                Oacc[1][dt] = MFMA16(pf1, vf, Oacc[1][dt]);
            }
        }
        mcur0 = mnxt0;
        mcur1 = mnxt1;
    }

    // ---- epilogue: folded scale 2*sqrt(D) = 16*sqrt(2)
    const float SCALE = 22.62741699796952f;
    #pragma unroll
    for (int rt = 0; rt < 2; ++rt)
        #pragma unroll
        for (int dt = 0; dt < 8; ++dt) {
            int row0 = 32*wave + 16*rt + 4*quad;
            #pragma unroll
            for (int r = 0; r < 4; ++r)
                __builtin_nontemporal_store(Oacc[rt][dt][r] * SCALE,
                    &optr[(size_t)(row0 + r)*D_ + 16*dt + ln]);
        }
}

extern "C" void kernel_launch(void* const* d_in, const int* in_sizes, int n_in,
                              void* d_out, int out_size, void* d_ws, size_t ws_size,
                              hipStream_t stream) {
    (void)in_sizes; (void)n_in; (void)ws_size; (void)out_size;
    const float* Q = (const float*)d_in[0];
    const float* K = (const float*)d_in[1];
    const float* V = (const float*)d_in[2];
    const int*   M = (const int*)d_in[3];
    float* Out = (float*)d_out;
    char* ws = (char*)d_ws;

    compress_mask<<<dim3(8192), 256, 0, stream>>>(M, ws);
    prep<<<dim3(B_*H_*(SK_/KT)), 256, 0, stream>>>(Q, K, V, ws);
    attn_drop_kernel<<<dim3(B_*H_*(SQ_/QT)), 256, 0, stream>>>(ws, Out);
}